// Round 3
// baseline (302.631 us; speedup 1.0000x reference)
//
#include <hip/hip_runtime.h>

#define NB 8
#define NC 256
#define IMG 3600
#define TEMPF 0.2f

typedef unsigned short u16;
typedef __bf16 bf16x8 __attribute__((ext_vector_type(8)));
typedef float  f32x4  __attribute__((ext_vector_type(4)));

__device__ __forceinline__ u16 f2bf(float f) {
  unsigned u = __builtin_bit_cast(unsigned, f);
  u += 0x7FFFu + ((u >> 16) & 1u);          // round-to-nearest-even
  return (u16)(u >> 16);
}

// ---------------------------------------------------------------------------
// Gather + transpose + bf16 cast:  des[b][m][c] = p[b][c][pix(m)]
// m >= M rows zero-filled (masked again in GEMM epilogue).
// ---------------------------------------------------------------------------
__global__ __launch_bounds__(256)
void gather_kernel(const float* __restrict__ p1, const float* __restrict__ p2,
                   const int* __restrict__ y1, const int* __restrict__ x1,
                   const int* __restrict__ y2, const int* __restrict__ x2,
                   u16* __restrict__ des1, u16* __restrict__ des2,
                   int M, int Mp) {
  __shared__ float tile[64][65];           // +1 pad: conflict-free transpose
  const int which = blockIdx.z >> 3;       // 0 -> des1, 1 -> des2
  const int b = blockIdx.z & 7;
  const float* P = (which ? p2 : p1) + (size_t)b * NC * IMG;
  const int* Y = which ? y2 : y1;
  const int* X = which ? x2 : x1;
  u16* D = (which ? des2 : des1) + (size_t)b * Mp * NC;
  const int m0 = blockIdx.x * 64, c0 = blockIdx.y * 64;
  const int t = threadIdx.x;

  const int lm = t & 63, cg = t >> 6;      // load: lane = m, 4 groups of c
  const int m = m0 + lm;
  const bool mv = m < M;
  const int pix = mv ? (Y[m] * 60 + X[m]) : 0;
#pragma unroll
  for (int cc = 0; cc < 16; ++cc) {
    int cl = cg * 16 + cc;
    tile[lm][cl] = mv ? P[(size_t)(c0 + cl) * IMG + pix] : 0.f;
  }
  __syncthreads();
  const int lc = t & 63, mg = t >> 6;      // store: lane = c (coalesced)
#pragma unroll
  for (int mm = 0; mm < 16; ++mm) {
    int ml = mg * 16 + mm;
    D[(size_t)(m0 + ml) * NC + (c0 + lc)] = f2bf(tile[ml][lc]);
  }
}

// ---------------------------------------------------------------------------
// Barrier-free MFMA GEMM + fused exp + row/col sum-of-exp + diag extraction.
// No LDS staging: A/B fragments loaded straight from global (L2-resident,
// 16B/lane dwordx4). K-loop has NO syncthreads -> loads pipeline freely.
// Block = 4 waves in 2x2; wave tile 64x64 = 4x4 of 16x16x32 bf16 MFMA.
// A frag: A[m=lane&15][k=quad*8+j]; B frag: B[n=lane&15][k=quad*8+j];
// C/D: col=lane&15, row=quad*4+reg.
// ---------------------------------------------------------------------------
__global__ __launch_bounds__(256)
void mfma_lse(const u16* __restrict__ des1, const u16* __restrict__ des2,
              float* __restrict__ row_sum, float* __restrict__ col_sum,
              float* __restrict__ diag, int M, int Mp) {
  __shared__ float rowAcc[128];
  __shared__ float colAcc[128];

  const int b = blockIdx.z;
  const int m0 = blockIdx.x * 128, n0 = blockIdx.y * 128;
  const int t = threadIdx.x;
  const int w = t >> 6, lane = t & 63;
  const int wm = w >> 1, wn = w & 1;
  const int quad = lane >> 4, l15 = lane & 15;

  // per-lane fragment base pointers (k-offset added in loop)
  const u16* A0 = des1 + ((size_t)b * Mp + m0 + wm * 64 + l15) * NC + quad * 8;
  const u16* B0 = des2 + ((size_t)b * Mp + n0 + wn * 64 + l15) * NC + quad * 8;

  f32x4 acc[4][4] = {};

  for (int k0 = 0; k0 < NC; k0 += 32) {
    bf16x8 af[4], bfr[4];
#pragma unroll
    for (int i = 0; i < 4; ++i)
      af[i] = *(const bf16x8*)(A0 + (size_t)(i * 16) * NC + k0);
#pragma unroll
    for (int j = 0; j < 4; ++j)
      bfr[j] = *(const bf16x8*)(B0 + (size_t)(j * 16) * NC + k0);
#pragma unroll
    for (int i = 0; i < 4; ++i)
#pragma unroll
      for (int j = 0; j < 4; ++j)
        acc[i][j] = __builtin_amdgcn_mfma_f32_16x16x32_bf16(
            af[i], bfr[j], acc[i][j], 0, 0, 0);
  }

  // ---- diagonal extraction (free): dist_diag = acc[i][i][r] on lane l15==row
  if (blockIdx.x == blockIdx.y && wm == wn) {
#pragma unroll
    for (int i = 0; i < 4; ++i)
#pragma unroll
      for (int r = 0; r < 4; ++r) {
        int row_l = wm * 64 + i * 16 + quad * 4 + r;
        if (l15 == quad * 4 + r && (m0 + row_l) < M)
          diag[b * M + m0 + row_l] = TEMPF * acc[i][i][r];
      }
  }

  if (t < 128) rowAcc[t] = 0.f; else colAcc[t - 128] = 0.f;
  __syncthreads();

  // epilogue: exp + reductions; pad rows/cols masked to 0.
  float cp[4] = {0.f, 0.f, 0.f, 0.f};
#pragma unroll
  for (int i = 0; i < 4; ++i) {
    const int rbase = wm * 64 + i * 16 + quad * 4;
#pragma unroll
    for (int r = 0; r < 4; ++r) {
      const int row_l = rbase + r;
      const bool mv = (m0 + row_l) < M;
      float rp = 0.f;
#pragma unroll
      for (int j = 0; j < 4; ++j) {
        const int col_l = wn * 64 + j * 16 + l15;
        const bool nv = (n0 + col_l) < M;
        float e = (mv && nv) ? __expf(TEMPF * acc[i][j][r]) : 0.f;
        rp += e;
        cp[j] += e;
      }
      rp += __shfl_xor(rp, 1);  rp += __shfl_xor(rp, 2);
      rp += __shfl_xor(rp, 4);  rp += __shfl_xor(rp, 8);
      if (l15 == 0) atomicAdd(&rowAcc[row_l], rp);
    }
  }
#pragma unroll
  for (int j = 0; j < 4; ++j) {
    float c = cp[j];
    c += __shfl_xor(c, 16);  c += __shfl_xor(c, 32);   // sum over quads (rows)
    if (quad == 0) atomicAdd(&colAcc[wn * 64 + j * 16 + l15], c);
  }
  __syncthreads();

  if (t < 128) {
    if (m0 + t < M) atomicAdd(&row_sum[b * M + m0 + t], rowAcc[t]);
  } else {
    int tt = t - 128;
    if (n0 + tt < M) atomicAdd(&col_sum[b * M + n0 + tt], colAcc[tt]);
  }
}

// ---------------------------------------------------------------------------
// loss partial: mean( log(row_sum) + log(col_sum) - 2*dist_diag )
// multi-block, one atomicAdd per block into pre-zeroed out[0].
// ---------------------------------------------------------------------------
__global__ __launch_bounds__(256)
void finalize(const float* __restrict__ row_sum, const float* __restrict__ col_sum,
              const float* __restrict__ diag, float* __restrict__ out,
              int total, float inv_total) {
  __shared__ float red[4];
  int i = blockIdx.x * 256 + threadIdx.x;
  float s = 0.f;
  if (i < total)
    s = logf(row_sum[i]) + logf(col_sum[i]) - 2.f * diag[i];
#pragma unroll
  for (int o = 1; o < 64; o <<= 1) s += __shfl_xor(s, o);
  const int lane = threadIdx.x & 63, wid = threadIdx.x >> 6;
  if (lane == 0) red[wid] = s;
  __syncthreads();
  if (threadIdx.x == 0)
    atomicAdd(out, (red[0] + red[1] + red[2] + red[3]) * inv_total);
}

extern "C" void kernel_launch(void* const* d_in, const int* in_sizes, int n_in,
                              void* d_out, int out_size, void* d_ws, size_t ws_size,
                              hipStream_t stream) {
  const float* p1 = (const float*)d_in[0];
  const float* p2 = (const float*)d_in[1];
  const int* y1 = (const int*)d_in[2];
  const int* x1 = (const int*)d_in[3];
  const int* y2 = (const int*)d_in[4];
  const int* x2 = (const int*)d_in[5];
  const int M = in_sizes[2];                    // 3540
  const int Mp = ((M + 127) / 128) * 128;       // 3584

  float* row_sum = (float*)d_ws;                // NB*M
  float* col_sum = row_sum + (size_t)NB * M;    // NB*M
  float* diagbuf = col_sum + (size_t)NB * M;    // NB*M
  size_t off = (((size_t)3 * NB * M * sizeof(float)) + 255) & ~(size_t)255;
  u16* des1 = (u16*)((char*)d_ws + off);        // NB*Mp*NC bf16
  u16* des2 = des1 + (size_t)NB * Mp * NC;

  hipMemsetAsync(d_ws, 0, (size_t)2 * NB * M * sizeof(float), stream);
  hipMemsetAsync(d_out, 0, sizeof(float), stream);

  dim3 ggrid(Mp / 64, NC / 64, 2 * NB);
  gather_kernel<<<ggrid, 256, 0, stream>>>(p1, p2, y1, x1, y2, x2, des1, des2, M, Mp);

  dim3 mgrid(Mp / 128, Mp / 128, NB);
  mfma_lse<<<mgrid, 256, 0, stream>>>(des1, des2, row_sum, col_sum, diagbuf, M, Mp);

  int total = NB * M;
  finalize<<<(total + 255) / 256, 256, 0, stream>>>(row_sum, col_sum, diagbuf,
                                                    (float*)d_out, total,
                                                    1.f / (float)total);
}

// Round 4
// 232.481 us; speedup vs baseline: 1.3017x; 1.3017x over previous
//
#include <hip/hip_runtime.h>

#define NB 8
#define NC 256          // K (u16 elements per descriptor row)
#define IMG 3600
#define TEMPF 0.2f

typedef unsigned short u16;
typedef __bf16 bf16x8 __attribute__((ext_vector_type(8)));
typedef float  f32x4  __attribute__((ext_vector_type(4)));
typedef unsigned short u16x8 __attribute__((ext_vector_type(8)));

__device__ __forceinline__ u16 f2bf(float f) {
  unsigned u = __builtin_bit_cast(unsigned, f);
  u += 0x7FFFu + ((u >> 16) & 1u);          // round-to-nearest-even
  return (u16)(u >> 16);
}

__device__ __forceinline__ void gld16(const void* g, void* l) {
  __builtin_amdgcn_global_load_lds(
      (__attribute__((address_space(1))) void*)g,
      (__attribute__((address_space(3))) void*)l, 16, 0, 0);
}

// ---------------------------------------------------------------------------
// Gather + transpose + bf16 cast.
//   des1 (which==0): plain  [b][row][k]            (A read direct to VGPR)
//   des2 (which==1): swizzled: 16B chunk c of row r stored at slot c^(r&31)
//     -> contiguous global_load_lds staging yields bank-conflict-free
//        ds_read_b128 fragment reads in the GEMM.
// Rows >= M zero-filled.
// ---------------------------------------------------------------------------
__global__ __launch_bounds__(256)
void gather_kernel(const float* __restrict__ p1, const float* __restrict__ p2,
                   const int* __restrict__ y1, const int* __restrict__ x1,
                   const int* __restrict__ y2, const int* __restrict__ x2,
                   u16* __restrict__ des1, u16* __restrict__ des2,
                   int M, int Mp) {
  __shared__ float tile[64][65];           // +1 pad: conflict-free transpose
  const int which = blockIdx.z >> 3;       // 0 -> des1, 1 -> des2
  const int b = blockIdx.z & 7;
  const float* P = (which ? p2 : p1) + (size_t)b * NC * IMG;
  const int* Y = which ? y2 : y1;
  const int* X = which ? x2 : x1;
  u16* D = (which ? des2 : des1) + (size_t)b * Mp * NC;
  const int m0 = blockIdx.x * 64, c0 = blockIdx.y * 64;
  const int t = threadIdx.x;

  const int lm = t & 63, cg = t >> 6;      // load: lane = m (near-contiguous pix)
  const int m = m0 + lm;
  const bool mv = m < M;
  const int pix = mv ? (Y[m] * 60 + X[m]) : 0;
#pragma unroll
  for (int cc = 0; cc < 16; ++cc) {
    int cl = cg * 16 + cc;
    tile[lm][cl] = mv ? P[(size_t)(c0 + cl) * IMG + pix] : 0.f;
  }
  __syncthreads();
  // store: 16-B chunks, swizzled slot for des2
#pragma unroll
  for (int s = 0; s < 2; ++s) {
    int idx = t + s * 256;
    int row_l = idx >> 3, ch_l = idx & 7;
    int row = m0 + row_l;
    int chunk = (c0 >> 3) + ch_l;
    int slot = which ? (chunk ^ (row & 31)) : chunk;
    u16x8 h;
#pragma unroll
    for (int k = 0; k < 8; ++k) h[k] = f2bf(tile[row_l][ch_l * 8 + k]);
    *(u16x8*)(D + (size_t)row * NC + slot * 8) = h;
  }
}

// ---------------------------------------------------------------------------
// Persistent row-block MFMA GEMM + fused exp / row / col / diag.
// Block = (m-tile of 128, batch b); loops over all 56 n-tiles of 64.
// 4 waves (wm,wn in 2x2): wave tile 64m x 32n = 4x2 of 16x16x32 bf16 MFMA.
// A (full K) in registers (af[4][8], loaded once). B double-buffered in LDS,
// pipelined with raw s_barrier + s_waitcnt vmcnt(8) (prev tile only) so the
// next tile's global_load_lds stays in flight across the barrier.
// ---------------------------------------------------------------------------
__global__ __launch_bounds__(256, 1)
void mfma_lse(const u16* __restrict__ des1, const u16* __restrict__ des2,
              float* __restrict__ row_sum, float* __restrict__ col_sum,
              float* __restrict__ diag, int M, int Mp) {
  __shared__ __align__(16) u16 buf[2][64 * NC];   // 2 x 32 KB = 64 KB exactly

  const int b = blockIdx.y;
  const int m0 = blockIdx.x * 128;
  const int t = threadIdx.x;
  const int w = t >> 6, lane = t & 63;
  const int wm = w >> 1, wn = w & 1;
  const int quad = lane >> 4, l15 = lane & 15;
  const int NT = Mp / 64;                          // 56 n-tiles

  const u16* Bb = des2 + (size_t)b * Mp * NC;

  // ---- prolog: stage B0, load A fragments to registers (once) ----
#pragma unroll
  for (int q = 0; q < 8; ++q)
    gld16(Bb + q * 2048 + t * 8, &buf[0][q * 2048 + t * 8]);

  const u16* Abase = des1 + ((size_t)b * Mp + m0 + wm * 64 + l15) * NC + quad * 8;
  bf16x8 af[4][8];
#pragma unroll
  for (int i = 0; i < 4; ++i)
#pragma unroll
    for (int ks = 0; ks < 8; ++ks)
      af[i][ks] = *(const bf16x8*)(Abase + (size_t)(i * 16) * NC + ks * 32);

  float rowReg[16];
#pragma unroll
  for (int i = 0; i < 16; ++i) rowReg[i] = 0.f;

  for (int nt = 0; nt < NT; ++nt) {
    if (nt + 1 < NT) {
      const u16* g = Bb + (size_t)(nt + 1) * 64 * NC;
      u16* l = buf[(nt + 1) & 1];
#pragma unroll
      for (int q = 0; q < 8; ++q)
        gld16(g + q * 2048 + t * 8, l + q * 2048 + t * 8);
      asm volatile("s_waitcnt vmcnt(8)" ::: "memory");  // tile nt resident
    } else {
      asm volatile("s_waitcnt vmcnt(0)" ::: "memory");
    }
    asm volatile("s_barrier" ::: "memory");             // all waves' nt loads done

    const u16* Bt = buf[nt & 1];
    f32x4 acc[4][2] = {};
#pragma unroll
    for (int ks = 0; ks < 8; ++ks) {
      bf16x8 bfr[2];
#pragma unroll
      for (int j = 0; j < 2; ++j) {
        int row = wn * 32 + j * 16 + l15;
        int slot = (ks * 4 + quad) ^ (row & 31);
        bfr[j] = *(const bf16x8*)(Bt + row * NC + slot * 8);
      }
#pragma unroll
      for (int i = 0; i < 4; ++i)
#pragma unroll
        for (int j = 0; j < 2; ++j)
          acc[i][j] = __builtin_amdgcn_mfma_f32_16x16x32_bf16(
              af[i][ks], bfr[j], acc[i][j], 0, 0, 0);
    }

    // ---- epilogue for this n-tile ----
    const int n0 = nt * 64;
    float cp0 = 0.f, cp1 = 0.f;
#pragma unroll
    for (int i = 0; i < 4; ++i) {
#pragma unroll
      for (int r = 0; r < 4; ++r) {
        const int rowg = m0 + wm * 64 + i * 16 + quad * 4 + r;
        const bool mv = rowg < M;
        const int c0g = n0 + wn * 32 + l15;
        float e0 = (mv && c0g < M)        ? __expf(TEMPF * acc[i][0][r]) : 0.f;
        float e1 = (mv && (c0g + 16) < M) ? __expf(TEMPF * acc[i][1][r]) : 0.f;
        cp0 += e0; cp1 += e1;
        rowReg[i * 4 + r] += e0 + e1;
      }
    }
    // col sums: reduce over quads (rows) then one atomic per col
#pragma unroll
    for (int j = 0; j < 2; ++j) {
      float c = j ? cp1 : cp0;
      c += __shfl_xor(c, 16); c += __shfl_xor(c, 32);
      int colg = n0 + wn * 32 + j * 16 + l15;
      if (quad == 0 && colg < M) atomicAdd(&col_sum[b * M + colg], c);
    }
    // diag: this wave's rows coincide with cols at nt == blockIdx.x*2 + wm
    if (nt == (int)blockIdx.x * 2 + wm) {
#pragma unroll
      for (int j = 0; j < 2; ++j) {
        int i = wn * 2 + j;
#pragma unroll
        for (int r = 0; r < 4; ++r) {
          int rowg = m0 + wm * 64 + i * 16 + quad * 4 + r;
          if (l15 == quad * 4 + r && rowg < M)
            diag[b * M + rowg] = TEMPF * acc[i][j][r];
        }
      }
    }

    asm volatile("s_waitcnt lgkmcnt(0)" ::: "memory");  // my Bt reads complete
    asm volatile("s_barrier" ::: "memory");             // before nt+2 overwrites
  }

  // ---- final row sums: reduce over l15 (cols), cross-wn via global atomic ----
#pragma unroll
  for (int i = 0; i < 4; ++i)
#pragma unroll
    for (int r = 0; r < 4; ++r) {
      float v = rowReg[i * 4 + r];
      v += __shfl_xor(v, 1); v += __shfl_xor(v, 2);
      v += __shfl_xor(v, 4); v += __shfl_xor(v, 8);
      int rowg = m0 + wm * 64 + i * 16 + quad * 4 + r;
      if (l15 == 0 && rowg < M) atomicAdd(&row_sum[b * M + rowg], v);
    }
}

// ---------------------------------------------------------------------------
// loss partial: mean( log(row_sum) + log(col_sum) - 2*dist_diag )
// ---------------------------------------------------------------------------
__global__ __launch_bounds__(256)
void finalize(const float* __restrict__ row_sum, const float* __restrict__ col_sum,
              const float* __restrict__ diag, float* __restrict__ out,
              int total, float inv_total) {
  __shared__ float red[4];
  int i = blockIdx.x * 256 + threadIdx.x;
  float s = 0.f;
  if (i < total)
    s = logf(row_sum[i]) + logf(col_sum[i]) - 2.f * diag[i];
#pragma unroll
  for (int o = 1; o < 64; o <<= 1) s += __shfl_xor(s, o);
  const int lane = threadIdx.x & 63, wid = threadIdx.x >> 6;
  if (lane == 0) red[wid] = s;
  __syncthreads();
  if (threadIdx.x == 0)
    atomicAdd(out, (red[0] + red[1] + red[2] + red[3]) * inv_total);
}

extern "C" void kernel_launch(void* const* d_in, const int* in_sizes, int n_in,
                              void* d_out, int out_size, void* d_ws, size_t ws_size,
                              hipStream_t stream) {
  const float* p1 = (const float*)d_in[0];
  const float* p2 = (const float*)d_in[1];
  const int* y1 = (const int*)d_in[2];
  const int* x1 = (const int*)d_in[3];
  const int* y2 = (const int*)d_in[4];
  const int* x2 = (const int*)d_in[5];
  const int M = in_sizes[2];                    // 3540
  const int Mp = ((M + 127) / 128) * 128;       // 3584

  float* row_sum = (float*)d_ws;                // NB*M
  float* col_sum = row_sum + (size_t)NB * M;    // NB*M
  float* diagbuf = col_sum + (size_t)NB * M;    // NB*M
  size_t off = (((size_t)3 * NB * M * sizeof(float)) + 255) & ~(size_t)255;
  u16* des1 = (u16*)((char*)d_ws + off);        // NB*Mp*NC bf16 (plain)
  u16* des2 = des1 + (size_t)NB * Mp * NC;      // NB*Mp*NC bf16 (swizzled)

  hipMemsetAsync(d_ws, 0, (size_t)2 * NB * M * sizeof(float), stream);
  hipMemsetAsync(d_out, 0, sizeof(float), stream);

  dim3 ggrid(Mp / 64, NC / 64, 2 * NB);
  gather_kernel<<<ggrid, 256, 0, stream>>>(p1, p2, y1, x1, y2, x2, des1, des2, M, Mp);

  dim3 mgrid(Mp / 128, NB);
  mfma_lse<<<mgrid, 256, 0, stream>>>(des1, des2, row_sum, col_sum, diagbuf, M, Mp);

  int total = NB * M;
  finalize<<<(total + 255) / 256, 256, 0, stream>>>(row_sum, col_sum, diagbuf,
                                                    (float*)d_out, total,
                                                    1.f / (float)total);
}

// Round 5
// 211.388 us; speedup vs baseline: 1.4316x; 1.0998x over previous
//
#include <hip/hip_runtime.h>

#define NB 8
#define NC 256          // K
#define IMG 3600
#define TEMPF 0.2f

typedef unsigned short u16;
typedef __bf16 bf16x8 __attribute__((ext_vector_type(8)));
typedef float  f32x4  __attribute__((ext_vector_type(4)));
typedef unsigned short u16x8 __attribute__((ext_vector_type(8)));

__device__ __forceinline__ u16 f2bf(float f) {
  unsigned u = __builtin_bit_cast(unsigned, f);
  u += 0x7FFFu + ((u >> 16) & 1u);          // round-to-nearest-even
  return (u16)(u >> 16);
}

// ---------------------------------------------------------------------------
// Gather + cast, k-chunk-major layout:
//   des[b][kc][row][j] = p[b][kc*8+j][pix(row)]   (kc = 0..31, j = 0..7)
// One thread builds one 16-B chunk from 8 coalesced strided reads.
// MFMA fragment loads then hit 4x256-B contiguous segments (lane=row).
// Rows >= M zero-filled.
// ---------------------------------------------------------------------------
__global__ __launch_bounds__(256)
void gather_kernel(const float* __restrict__ p1, const float* __restrict__ p2,
                   const int* __restrict__ y1, const int* __restrict__ x1,
                   const int* __restrict__ y2, const int* __restrict__ x2,
                   u16* __restrict__ des1, u16* __restrict__ des2,
                   int M, int Mp) {
  const int which = blockIdx.z >> 3;       // 0 -> des1, 1 -> des2
  const int b = blockIdx.z & 7;
  const float* P = (which ? p2 : p1) + (size_t)b * NC * IMG;
  const int* Y = which ? y2 : y1;
  const int* X = which ? x2 : x1;
  u16* D = (which ? des2 : des1) + (size_t)b * Mp * NC;

  const int t = threadIdx.x;
  const int row_l = t & 63;                // lane = row -> coalesced store
  const int kc = blockIdx.y * 4 + (t >> 6);
  const int m = blockIdx.x * 64 + row_l;
  const bool mv = m < M;
  const int pix = mv ? (Y[m] * 60 + X[m]) : 0;
  const float* src = P + (size_t)(kc * 8) * IMG + pix;

  u16x8 h;
#pragma unroll
  for (int j = 0; j < 8; ++j) {
    float v = mv ? src[(size_t)j * IMG] : 0.f;
    h[j] = f2bf(v);
  }
  *(u16x8*)(D + ((size_t)kc * Mp + m) * 8) = h;
}

// ---------------------------------------------------------------------------
// Barrier-free, LDS-free MFMA GEMM + fused exp / row / col / diag.
// Block = 64 A-rows x full n-range for one batch; batch = blockIdx&7 (XCD pin,
// keeps that batch's B L2-resident). 4 waves sweep disjoint 16-col strips
// (ns = w + 4*s). A (64 x 256) lives in VGPRs, loaded once. B fragments
// ping-pong double-buffered in registers -> next strip's loads in flight
// across current strip's MFMAs, no waitcnt(0), no barriers.
// Frag layouts (16x16x32 bf16): A/B[row=l15][k=quad*8+j]; C/D col=l15,
// row=quad*4+reg.
// ---------------------------------------------------------------------------
__global__ __launch_bounds__(256, 2)
void mfma_lse(const u16* __restrict__ des1, const u16* __restrict__ des2,
              float* __restrict__ row_sum, float* __restrict__ col_sum,
              float* __restrict__ diag, int M, int Mp) {
  const int b  = blockIdx.x & 7;
  const int mt = blockIdx.x >> 3;
  const int m0 = mt * 64;
  const int t = threadIdx.x;
  const int w = t >> 6, lane = t & 63;
  const int quad = lane >> 4, l15 = lane & 15;

  const u16* D1 = des1 + (size_t)b * Mp * NC;
  const u16* D2 = des2 + (size_t)b * Mp * NC;

  // ---- A fragments, full K, loaded once ----
  bf16x8 af[4][8];
#pragma unroll
  for (int i = 0; i < 4; ++i)
#pragma unroll
    for (int ks = 0; ks < 8; ++ks)
      af[i][ks] = *(const bf16x8*)(
          D1 + ((size_t)(ks * 4 + quad) * Mp + m0 + i * 16 + l15) * 8);

  float rowReg[16];
#pragma unroll
  for (int i = 0; i < 16; ++i) rowReg[i] = 0.f;

  auto loadB = [&](bf16x8 (&dst)[8], int ns) {
#pragma unroll
    for (int ks = 0; ks < 8; ++ks)
      dst[ks] = *(const bf16x8*)(
          D2 + ((size_t)(ks * 4 + quad) * Mp + ns * 16 + l15) * 8);
  };

  auto do_strip = [&](const bf16x8 (&bfr)[8], int ns) {
    f32x4 acc[4] = {};
#pragma unroll
    for (int ks = 0; ks < 8; ++ks)
#pragma unroll
      for (int i = 0; i < 4; ++i)
        acc[i] = __builtin_amdgcn_mfma_f32_16x16x32_bf16(
            af[i][ks], bfr[ks], acc[i], 0, 0, 0);

    const int colg = ns * 16 + l15;
    const bool nv = colg < M;
    float cp = 0.f;
#pragma unroll
    for (int i = 0; i < 4; ++i)
#pragma unroll
      for (int r = 0; r < 4; ++r) {
        const int rowg = m0 + i * 16 + quad * 4 + r;
        float e = (nv && rowg < M) ? __expf(TEMPF * acc[i][r]) : 0.f;
        rowReg[i * 4 + r] += e;
        cp += e;
      }
    cp += __shfl_xor(cp, 16);
    cp += __shfl_xor(cp, 32);
    if (quad == 0 && nv) atomicAdd(&col_sum[b * M + colg], cp);

    // diag: strip ns covers cols [ns*16, ns*16+16); diagonal rows live in
    // strips mt*4 .. mt*4+3 (one per wave since ns % 4 == w).
#pragma unroll
    for (int i = 0; i < 4; ++i)
      if (ns == mt * 4 + i) {
#pragma unroll
        for (int r = 0; r < 4; ++r) {
          int rowg = m0 + i * 16 + quad * 4 + r;
          if (l15 == quad * 4 + r && rowg < M)
            diag[b * M + rowg] = TEMPF * acc[i][r];
        }
      }
  };

  // ---- strip loop, ping-pong B double-buffer (56 strips per wave) ----
  const int nPer = (Mp >> 4) >> 2;   // 56
  bf16x8 bcur[8], bnxt[8];
  int ns = w;
  loadB(bcur, ns);
  for (int s = 0; s < nPer; s += 2) {
    loadB(bnxt, ns + 4);             // strip s+1 (always exists: nPer even)
    do_strip(bcur, ns);
    if (s + 2 < nPer) loadB(bcur, ns + 8);
    do_strip(bnxt, ns + 4);
    ns += 8;
  }

  // ---- row sums: reduce over the 16 cols (l15) of this wave's strips ----
#pragma unroll
  for (int i = 0; i < 4; ++i)
#pragma unroll
    for (int r = 0; r < 4; ++r) {
      float v = rowReg[i * 4 + r];
      v += __shfl_xor(v, 1); v += __shfl_xor(v, 2);
      v += __shfl_xor(v, 4); v += __shfl_xor(v, 8);
      int rowg = m0 + i * 16 + quad * 4 + r;
      if (l15 == 0 && rowg < M) atomicAdd(&row_sum[b * M + rowg], v);
    }
}

// ---------------------------------------------------------------------------
// loss partial: mean( log(row_sum) + log(col_sum) - 2*dist_diag )
// ---------------------------------------------------------------------------
__global__ __launch_bounds__(256)
void finalize(const float* __restrict__ row_sum, const float* __restrict__ col_sum,
              const float* __restrict__ diag, float* __restrict__ out,
              int total, float inv_total) {
  __shared__ float red[4];
  int i = blockIdx.x * 256 + threadIdx.x;
  float s = 0.f;
  if (i < total)
    s = logf(row_sum[i]) + logf(col_sum[i]) - 2.f * diag[i];
#pragma unroll
  for (int o = 1; o < 64; o <<= 1) s += __shfl_xor(s, o);
  const int lane = threadIdx.x & 63, wid = threadIdx.x >> 6;
  if (lane == 0) red[wid] = s;
  __syncthreads();
  if (threadIdx.x == 0)
    atomicAdd(out, (red[0] + red[1] + red[2] + red[3]) * inv_total);
}

extern "C" void kernel_launch(void* const* d_in, const int* in_sizes, int n_in,
                              void* d_out, int out_size, void* d_ws, size_t ws_size,
                              hipStream_t stream) {
  const float* p1 = (const float*)d_in[0];
  const float* p2 = (const float*)d_in[1];
  const int* y1 = (const int*)d_in[2];
  const int* x1 = (const int*)d_in[3];
  const int* y2 = (const int*)d_in[4];
  const int* x2 = (const int*)d_in[5];
  const int M = in_sizes[2];                    // 3540
  const int Mp = ((M + 63) / 64) * 64;          // 3584

  float* row_sum = (float*)d_ws;                // NB*M
  float* col_sum = row_sum + (size_t)NB * M;    // NB*M
  float* diagbuf = col_sum + (size_t)NB * M;    // NB*M
  size_t off = (((size_t)3 * NB * M * sizeof(float)) + 255) & ~(size_t)255;
  u16* des1 = (u16*)((char*)d_ws + off);        // NB*Mp*NC bf16, k-chunk-major
  u16* des2 = des1 + (size_t)NB * Mp * NC;

  hipMemsetAsync(d_ws, 0, (size_t)2 * NB * M * sizeof(float), stream);
  hipMemsetAsync(d_out, 0, sizeof(float), stream);

  dim3 ggrid(Mp / 64, NC / 32, 2 * NB);         // (56, 8, 16)
  gather_kernel<<<ggrid, 256, 0, stream>>>(p1, p2, y1, x1, y2, x2, des1, des2, M, Mp);

  mfma_lse<<<dim3(NB * Mp / 64), 256, 0, stream>>>(des1, des2, row_sum, col_sum,
                                                   diagbuf, M, Mp);

  int total = NB * M;
  finalize<<<(total + 255) / 256, 256, 0, stream>>>(row_sum, col_sum, diagbuf,
                                                    (float*)d_out, total,
                                                    1.f / (float)total);
}